// Round 1
// baseline (564.306 us; speedup 1.0000x reference)
//
#include <hip/hip_runtime.h>
#include <math.h>

#define B_ 64
#define T_ 2048
#define D_ 512
#define A_ 128

// ---------------- Kernel 1: scores GEMM + tanh epilogue ----------------
// Tile: 64 tokens x 128 (all A), K chunks of 64. fp32 vector FMA.
#define KB 64
#define TM 64
#define XPAD 68   // 64 + 4 pad: keeps 16B alignment for ds_read_b128, breaks bank aliasing

__global__ __launch_bounds__(256) void scores_kernel(
    const float* __restrict__ x, const float* __restrict__ W1,
    const float* __restrict__ b1, const float* __restrict__ W2,
    const float* __restrict__ b2, float* __restrict__ scores)
{
    __shared__ float xT[KB][XPAD];      // transposed x tile: xT[k][m]
    __shared__ float w1s[KB][A_];       // W1 tile: w1s[k][n]
    __shared__ float part[TM][17];      // per-token partials across 16 n-groups

    const int tid = threadIdx.x;
    const long mbase = (long)blockIdx.x * TM;
    const float* xrow = x + mbase * D_;

    float acc[4][8];
#pragma unroll
    for (int i = 0; i < 4; i++)
#pragma unroll
        for (int j = 0; j < 8; j++) acc[i][j] = 0.0f;

    const int tm = (tid & 15) * 4;   // 4 consecutive tokens
    const int tn = (tid >> 4) * 8;   // 8 consecutive A-columns

    for (int kc = 0; kc < D_; kc += KB) {
        // stage x tile (transposed into LDS)
#pragma unroll
        for (int j = 0; j < 4; j++) {
            int m  = (tid >> 4) + j * 16;
            int kv = (tid & 15) * 4;
            float4 v = *(const float4*)(xrow + (long)m * D_ + kc + kv);
            xT[kv + 0][m] = v.x;
            xT[kv + 1][m] = v.y;
            xT[kv + 2][m] = v.z;
            xT[kv + 3][m] = v.w;
        }
        // stage W1 tile
#pragma unroll
        for (int j = 0; j < 8; j++) {
            int r = (tid >> 5) + j * 8;
            int c = (tid & 31) * 4;
            *(float4*)&w1s[r][c] = *(const float4*)(W1 + (long)(kc + r) * A_ + c);
        }
        __syncthreads();

#pragma unroll 8
        for (int k = 0; k < KB; k++) {
            float4 xv = *(const float4*)&xT[k][tm];
            float4 wa = *(const float4*)&w1s[k][tn];
            float4 wb = *(const float4*)&w1s[k][tn + 4];
            const float xs[4] = {xv.x, xv.y, xv.z, xv.w};
            const float ws[8] = {wa.x, wa.y, wa.z, wa.w, wb.x, wb.y, wb.z, wb.w};
#pragma unroll
            for (int i = 0; i < 4; i++)
#pragma unroll
                for (int j = 0; j < 8; j++)
                    acc[i][j] = fmaf(xs[i], ws[j], acc[i][j]);
        }
        __syncthreads();
    }

    // epilogue: p[token] += tanh(acc + b1[n]) * W2[n]
    float p[4] = {0.f, 0.f, 0.f, 0.f};
#pragma unroll
    for (int j = 0; j < 8; j++) {
        float bb = b1[tn + j];
        float ww = W2[tn + j];
#pragma unroll
        for (int i = 0; i < 4; i++)
            p[i] += tanhf(acc[i][j] + bb) * ww;
    }
#pragma unroll
    for (int i = 0; i < 4; i++) part[tm + i][tid >> 4] = p[i];
    __syncthreads();

    if (tid < TM) {
        float s = b2[0];
#pragma unroll
        for (int g = 0; g < 16; g++) s += part[tid][g];
        scores[mbase + tid] = s;
    }
}

// ---------------- Kernel 2: softmax over T per batch ----------------
__global__ __launch_bounds__(256) void softmax_kernel(
    const float* __restrict__ scores, float* __restrict__ w)
{
    const int b = blockIdx.x;
    const int tid = threadIdx.x;
    const float* s = scores + (long)b * T_;

    float v[8];
    float mx = -1e30f;
#pragma unroll
    for (int j = 0; j < 8; j++) {
        v[j] = s[tid + j * 256];
        mx = fmaxf(mx, v[j]);
    }
#pragma unroll
    for (int off = 1; off < 64; off <<= 1)
        mx = fmaxf(mx, __shfl_xor(mx, off, 64));
    __shared__ float redm[4];
    if ((tid & 63) == 0) redm[tid >> 6] = mx;
    __syncthreads();
    mx = fmaxf(fmaxf(redm[0], redm[1]), fmaxf(redm[2], redm[3]));

    float sum = 0.f;
#pragma unroll
    for (int j = 0; j < 8; j++) {
        v[j] = __expf(v[j] - mx);
        sum += v[j];
    }
#pragma unroll
    for (int off = 1; off < 64; off <<= 1)
        sum += __shfl_xor(sum, off, 64);
    __shared__ float reds[4];
    if ((tid & 63) == 0) reds[tid >> 6] = sum;
    __syncthreads();
    sum = reds[0] + reds[1] + reds[2] + reds[3];
    const float inv = 1.0f / sum;
#pragma unroll
    for (int j = 0; j < 8; j++)
        w[(long)b * T_ + tid + j * 256] = v[j] * inv;
}

// ---------------- Kernel 3: weighted pooling (mu, std) ----------------
// grid: 64 batches x 8 d-chunks of 64. threads: 16 d-float4 x 16 t-groups.
__global__ __launch_bounds__(256) void pool_kernel(
    const float* __restrict__ x, const float* __restrict__ w,
    float* __restrict__ out)
{
    const int blk = blockIdx.x;
    const int b = blk >> 3;
    const int dbase = (blk & 7) * 64;
    const int tid = threadIdx.x;
    const int dthr = tid & 15;
    const int tg = tid >> 4;

    const float* xb = x + (long)b * T_ * D_ + dbase + dthr * 4;
    const float* wb = w + (long)b * T_;

    float4 mu = {0.f, 0.f, 0.f, 0.f};
    float4 m2 = {0.f, 0.f, 0.f, 0.f};

#pragma unroll 4
    for (int t = tg; t < T_; t += 16) {
        float wt = wb[t];
        float4 xv = *(const float4*)(xb + (long)t * D_);
        mu.x = fmaf(wt, xv.x, mu.x);
        mu.y = fmaf(wt, xv.y, mu.y);
        mu.z = fmaf(wt, xv.z, mu.z);
        mu.w = fmaf(wt, xv.w, mu.w);
        m2.x = fmaf(wt * xv.x, xv.x, m2.x);
        m2.y = fmaf(wt * xv.y, xv.y, m2.y);
        m2.z = fmaf(wt * xv.z, xv.z, m2.z);
        m2.w = fmaf(wt * xv.w, xv.w, m2.w);
    }

    __shared__ float4 smu[16][16];
    __shared__ float4 sm2[16][16];
    smu[tg][dthr] = mu;
    sm2[tg][dthr] = m2;
    __syncthreads();

    if (tid < 16) {
        float4 M = {0.f, 0.f, 0.f, 0.f};
        float4 S = {0.f, 0.f, 0.f, 0.f};
#pragma unroll
        for (int g = 0; g < 16; g++) {
            float4 a = smu[g][tid];
            M.x += a.x; M.y += a.y; M.z += a.z; M.w += a.w;
            float4 c = sm2[g][tid];
            S.x += c.x; S.y += c.y; S.z += c.z; S.w += c.w;
        }
        float4 sd;
        sd.x = sqrtf(fmaxf(S.x - M.x * M.x, 0.f) + 1e-6f);
        sd.y = sqrtf(fmaxf(S.y - M.y * M.y, 0.f) + 1e-6f);
        sd.z = sqrtf(fmaxf(S.z - M.z * M.z, 0.f) + 1e-6f);
        sd.w = sqrtf(fmaxf(S.w - M.w * M.w, 0.f) + 1e-6f);
        *(float4*)(out + (long)b * (2 * D_) + dbase + tid * 4) = M;
        *(float4*)(out + (long)b * (2 * D_) + D_ + dbase + tid * 4) = sd;
    }
}

extern "C" void kernel_launch(void* const* d_in, const int* in_sizes, int n_in,
                              void* d_out, int out_size, void* d_ws, size_t ws_size,
                              hipStream_t stream) {
    const float* x  = (const float*)d_in[0];
    const float* W1 = (const float*)d_in[1];
    const float* b1 = (const float*)d_in[2];
    const float* W2 = (const float*)d_in[3];
    const float* b2 = (const float*)d_in[4];
    float* out = (float*)d_out;

    float* scores = (float*)d_ws;                       // B*T floats
    float* w      = scores + (long)B_ * T_;             // B*T floats

    scores_kernel<<<(B_ * T_) / TM, 256, 0, stream>>>(x, W1, b1, W2, b2, scores);
    softmax_kernel<<<B_, 256, 0, stream>>>(scores, w);
    pool_kernel<<<B_ * 8, 256, 0, stream>>>(x, w, out);
}

// Round 2
// 428.229 us; speedup vs baseline: 1.3178x; 1.3178x over previous
//
#include <hip/hip_runtime.h>
#include <hip/hip_bf16.h>
#include <math.h>

#define B_ 64
#define T_ 2048
#define D_ 512
#define A_ 128

typedef __bf16 bf16x8 __attribute__((ext_vector_type(8)));
typedef float  f32x4  __attribute__((ext_vector_type(4)));

// ---------------- Kernel 0: W1 [512][128] fp32 -> W1T [128][512] bf16 ----------------
__global__ __launch_bounds__(256) void prep_kernel(
    const float* __restrict__ W1, __hip_bfloat16* __restrict__ W1T)
{
    int idx = blockIdx.x * 256 + threadIdx.x;   // 64K elements, grid 256
    int k = idx >> 7;          // 0..511
    int n = idx & 127;         // 0..127
    W1T[n * D_ + k] = __float2bfloat16(W1[idx]);
}

// ---------------- Kernel 1: scores via bf16 MFMA, operands swapped ----------------
// D[n][token] = sum_k W1T[n][k] * x[token][k].  A = W1T (16B contig), B = x (16B contig).
__device__ inline bf16x8 cvt8(float4 a, float4 b) {
    bf16x8 r;
    r[0] = (__bf16)a.x; r[1] = (__bf16)a.y; r[2] = (__bf16)a.z; r[3] = (__bf16)a.w;
    r[4] = (__bf16)b.x; r[5] = (__bf16)b.y; r[6] = (__bf16)b.z; r[7] = (__bf16)b.w;
    return r;
}

__device__ inline float fast_tanh(float v) {
    v = fminf(fmaxf(v, -15.f), 15.f);
    float e = __expf(2.f * v);
    return (e - 1.f) / (e + 1.f);
}

__global__ __launch_bounds__(256) void scores_kernel(
    const float* __restrict__ x, const __hip_bfloat16* __restrict__ W1T_,
    const float* __restrict__ b1, const float* __restrict__ W2,
    const float* __restrict__ b2, float* __restrict__ scores)
{
    const __bf16* W1T = (const __bf16*)W1T_;
    const int tid  = threadIdx.x;
    const int wave = tid >> 6;
    const int lane = tid & 63;
    const int col  = lane & 15;    // token within 16-tile (and A-row select)
    const int kgrp = lane >> 4;    // 0..3

    const long tokbase = (long)blockIdx.x * 128 + wave * 32;

    f32x4 acc[8][2];
#pragma unroll
    for (int mt = 0; mt < 8; mt++) {
        acc[mt][0] = (f32x4){0.f, 0.f, 0.f, 0.f};
        acc[mt][1] = (f32x4){0.f, 0.f, 0.f, 0.f};
    }

    const float* xp0 = x + (tokbase + col) * D_;        // token tile 0
    const float* xp1 = xp0 + 16 * D_;                   // token tile 1
    const __bf16* wp = W1T + (long)col * D_;            // row col of each 16-row A tile

#pragma unroll 2
    for (int ks = 0; ks < 16; ks++) {
        const int klane = ks * 32 + kgrp * 8;
        float4 b0a = *(const float4*)(xp0 + klane);
        float4 b0b = *(const float4*)(xp0 + klane + 4);
        float4 b1a = *(const float4*)(xp1 + klane);
        float4 b1b = *(const float4*)(xp1 + klane + 4);
        bf16x8 bf0 = cvt8(b0a, b0b);
        bf16x8 bf1 = cvt8(b1a, b1b);
#pragma unroll
        for (int mt = 0; mt < 8; mt++) {
            bf16x8 af = *(const bf16x8*)(wp + (long)mt * 16 * D_ + klane);
            acc[mt][0] = __builtin_amdgcn_mfma_f32_16x16x32_bf16(af, bf0, acc[mt][0], 0, 0, 0);
            acc[mt][1] = __builtin_amdgcn_mfma_f32_16x16x32_bf16(af, bf1, acc[mt][1], 0, 0, 0);
        }
    }

    // epilogue: n = mt*16 + kgrp*4 + r ; token = tokbase + tt*16 + col
    float p0 = 0.f, p1 = 0.f;
#pragma unroll
    for (int mt = 0; mt < 8; mt++) {
#pragma unroll
        for (int r = 0; r < 4; r++) {
            int n = mt * 16 + kgrp * 4 + r;
            float bb = b1[n];
            float ww = W2[n];
            p0 += fast_tanh(acc[mt][0][r] + bb) * ww;
            p1 += fast_tanh(acc[mt][1][r] + bb) * ww;
        }
    }
    p0 += __shfl_xor(p0, 16, 64);
    p0 += __shfl_xor(p0, 32, 64);
    p1 += __shfl_xor(p1, 16, 64);
    p1 += __shfl_xor(p1, 32, 64);
    if (lane < 16) {
        float bias = b2[0];
        scores[tokbase + col]      = p0 + bias;
        scores[tokbase + 16 + col] = p1 + bias;
    }
}

// ---------------- Kernel 2: softmax over T per batch ----------------
__global__ __launch_bounds__(256) void softmax_kernel(
    const float* __restrict__ scores, float* __restrict__ w)
{
    const int b = blockIdx.x;
    const int tid = threadIdx.x;
    const float* s = scores + (long)b * T_;

    float v[8];
    float mx = -1e30f;
#pragma unroll
    for (int j = 0; j < 8; j++) {
        v[j] = s[tid + j * 256];
        mx = fmaxf(mx, v[j]);
    }
#pragma unroll
    for (int off = 1; off < 64; off <<= 1)
        mx = fmaxf(mx, __shfl_xor(mx, off, 64));
    __shared__ float redm[4];
    if ((tid & 63) == 0) redm[tid >> 6] = mx;
    __syncthreads();
    mx = fmaxf(fmaxf(redm[0], redm[1]), fmaxf(redm[2], redm[3]));

    float sum = 0.f;
#pragma unroll
    for (int j = 0; j < 8; j++) {
        v[j] = __expf(v[j] - mx);
        sum += v[j];
    }
#pragma unroll
    for (int off = 1; off < 64; off <<= 1)
        sum += __shfl_xor(sum, off, 64);
    __shared__ float reds[4];
    if ((tid & 63) == 0) reds[tid >> 6] = sum;
    __syncthreads();
    sum = reds[0] + reds[1] + reds[2] + reds[3];
    const float inv = 1.0f / sum;
#pragma unroll
    for (int j = 0; j < 8; j++)
        w[(long)b * T_ + tid + j * 256] = v[j] * inv;
}

// ---------------- Kernel 3: pooling partials (contiguous rows) ----------------
// grid: 64 b x 8 chunks of 256 tokens. 256 threads: 2 full rows (512 f) per iter.
__global__ __launch_bounds__(256) void pool_partial_kernel(
    const float* __restrict__ x, const float* __restrict__ w,
    float* __restrict__ pmu, float* __restrict__ pm2)
{
    const int blk = blockIdx.x;
    const int b = blk >> 3;
    const int t0 = (blk & 7) * 256;
    const int tid = threadIdx.x;
    const int half = tid >> 7;        // 0/1: which of 2 rows per iter
    const int dq = tid & 127;         // float4 index over D=512

    const float* wb = w + (long)b * T_ + t0;
    const float* xb = x + ((long)b * T_ + t0) * D_ + dq * 4;

    float4 mu = {0.f, 0.f, 0.f, 0.f};
    float4 m2 = {0.f, 0.f, 0.f, 0.f};

#pragma unroll 4
    for (int t = half; t < 256; t += 2) {
        float wt = wb[t];
        float4 xv = *(const float4*)(xb + (long)t * D_);
        mu.x = fmaf(wt, xv.x, mu.x);
        mu.y = fmaf(wt, xv.y, mu.y);
        mu.z = fmaf(wt, xv.z, mu.z);
        mu.w = fmaf(wt, xv.w, mu.w);
        m2.x = fmaf(wt * xv.x, xv.x, m2.x);
        m2.y = fmaf(wt * xv.y, xv.y, m2.y);
        m2.z = fmaf(wt * xv.z, xv.z, m2.z);
        m2.w = fmaf(wt * xv.w, xv.w, m2.w);
    }

    __shared__ float4 smu[256];
    __shared__ float4 sm2[256];
    smu[tid] = mu;
    sm2[tid] = m2;
    __syncthreads();

    if (tid < 128) {
        float4 a = smu[tid], c = smu[tid + 128];
        float4 e = sm2[tid], f = sm2[tid + 128];
        a.x += c.x; a.y += c.y; a.z += c.z; a.w += c.w;
        e.x += f.x; e.y += f.y; e.z += f.z; e.w += f.w;
        *(float4*)(pmu + (long)blk * D_ + dq * 4) = a;
        *(float4*)(pm2 + (long)blk * D_ + dq * 4) = e;
    }
}

// ---------------- Kernel 4: final reduce ----------------
__global__ __launch_bounds__(256) void pool_final_kernel(
    const float* __restrict__ pmu, const float* __restrict__ pm2,
    float* __restrict__ out)
{
    const int b = blockIdx.x;
    const int tid = threadIdx.x;
#pragma unroll
    for (int i = 0; i < 2; i++) {
        int d = tid + i * 256;
        float mu = 0.f, m2 = 0.f;
#pragma unroll
        for (int c = 0; c < 8; c++) {
            mu += pmu[((long)b * 8 + c) * D_ + d];
            m2 += pm2[((long)b * 8 + c) * D_ + d];
        }
        out[(long)b * (2 * D_) + d] = mu;
        out[(long)b * (2 * D_) + D_ + d] = sqrtf(fmaxf(m2 - mu * mu, 0.f) + 1e-6f);
    }
}

extern "C" void kernel_launch(void* const* d_in, const int* in_sizes, int n_in,
                              void* d_out, int out_size, void* d_ws, size_t ws_size,
                              hipStream_t stream) {
    const float* x  = (const float*)d_in[0];
    const float* W1 = (const float*)d_in[1];
    const float* b1 = (const float*)d_in[2];
    const float* W2 = (const float*)d_in[3];
    const float* b2 = (const float*)d_in[4];
    float* out = (float*)d_out;

    float* ws = (float*)d_ws;
    float* scores = ws;                                   // 131072 f
    float* w      = ws + (long)B_ * T_;                   // 131072 f
    float* pmu    = ws + 2L * B_ * T_;                    // 512*512 f
    float* pm2    = pmu + 512L * D_;                      // 512*512 f
    __hip_bfloat16* W1T = (__hip_bfloat16*)(pm2 + 512L * D_);  // 65536 bf16

    prep_kernel<<<256, 256, 0, stream>>>(W1, W1T);
    scores_kernel<<<(B_ * T_) / 128, 256, 0, stream>>>(x, W1T, b1, W2, b2, scores);
    softmax_kernel<<<B_, 256, 0, stream>>>(scores, w);
    pool_partial_kernel<<<B_ * 8, 256, 0, stream>>>(x, w, pmu, pm2);
    pool_final_kernel<<<B_, 256, 0, stream>>>(pmu, pm2, out);
}